// Round 12
// baseline (2327.625 us; speedup 1.0000x reference)
//
#include <hip/hip_runtime.h>
#include <cmath>

// Problem constants (from reference setup_inputs)
#define Bc 8
#define Nc 4096
#define Sc 1024
#define Kc 32
#define Mc (Bc*Sc*Kc)   // 262144 rows

typedef float v2f __attribute__((ext_vector_type(2)));

__device__ __forceinline__ float gelu_f(float x){
  return 0.5f*x*(1.0f + erff(x*0.70710678f));
}

// Packed f32 ops via inline asm (non-volatile: scheduler may reorder freely).
// Per-element IEEE RN, immune to FMA contraction.
__device__ __forceinline__ v2f pk_add(v2f a, v2f b){
  v2f d; asm("v_pk_add_f32 %0, %1, %2" : "=v"(d) : "v"(a), "v"(b)); return d;
}
__device__ __forceinline__ v2f pk_mul(v2f a, v2f b){
  v2f d; asm("v_pk_mul_f32 %0, %1, %2" : "=v"(d) : "v"(a), "v"(b)); return d;
}

// DPP max-reduction steps (VALU-speed cross-lane). row_ror:n = 0x120|n.
#define ROR_MAXF(v, n) { int _t = __builtin_amdgcn_update_dpp(__float_as_int(v), __float_as_int(v), 0x120|(n), 0xF, 0xF, false); \
                         v = fmaxf(v, __int_as_float(_t)); }
#define BC15_MAXF(v)   { int _t = __builtin_amdgcn_update_dpp(__float_as_int(v), __float_as_int(v), 0x142, 0xA, 0xF, false); \
                         v = fmaxf(v, __int_as_float(_t)); }
#define BC31_MAXF(v)   { int _t = __builtin_amdgcn_update_dpp(__float_as_int(v), __float_as_int(v), 0x143, 0xC, 0xF, false); \
                         v = fmaxf(v, __int_as_float(_t)); }

// ---------------- fused front: blocks 0-7 FPS (1 wave), 8-519 transpose, 520 tp-MLP ----------------
__global__ __launch_bounds__(256, 1) void fused_front_kernel(
    const float* __restrict__ xyz, float* __restrict__ new_xyz,
    const float* __restrict__ points, float* __restrict__ pointsT,
    const float* __restrict__ t_embed,
    const float* __restrict__ wt0, const float* __restrict__ bt0,
    const float* __restrict__ wt1, const float* __restrict__ bt1,
    const float* __restrict__ wt2, const float* __restrict__ bt2,
    float* __restrict__ tp)
{
  __shared__ __align__(16) float smem[16384];   // 64 KB pool (FPS coord stash)
  const int bid = blockIdx.x;
  const int tid = threadIdx.x;

  if (bid < 8){
    // ================= FPS: single wave owns all 4096 points =================
    // No barriers, no cross-wave LDS. Lane owns points [lane*64, lane*64+64).
    // Bitwise-exact vs numpy: ((dx*dx+dy*dy)+dz*dz), fmin, argmax tie->lowest idx.
    if (tid >= 64) return;                      // waves 1..3 exit
    const int b = bid;
    const int lane = tid;
    const float* xb = xyz + b*Nc*3;
    float4* c4 = (float4*)smem;                 // [4096] coord stash (winner lookup)
    const int base = lane << 6;                 // first owned point

    v2f px2[32], py2[32], pz2[32], d2[32];
    const float4* src = (const float4*)(xb + (size_t)base*3);
#pragma unroll
    for (int c=0;c<8;++c){                      // 8 chunks x 8 points (24 floats)
      const float4 f0=src[6*c+0], f1=src[6*c+1], f2=src[6*c+2];
      const float4 f3=src[6*c+3], f4=src[6*c+4], f5=src[6*c+5];
      px2[4*c+0]=(v2f){f0.x,f0.w}; py2[4*c+0]=(v2f){f0.y,f1.x}; pz2[4*c+0]=(v2f){f0.z,f1.y};
      px2[4*c+1]=(v2f){f1.z,f2.y}; py2[4*c+1]=(v2f){f1.w,f2.z}; pz2[4*c+1]=(v2f){f2.x,f2.w};
      px2[4*c+2]=(v2f){f3.x,f3.w}; py2[4*c+2]=(v2f){f3.y,f4.x}; pz2[4*c+2]=(v2f){f3.z,f4.y};
      px2[4*c+3]=(v2f){f4.z,f5.y}; py2[4*c+3]=(v2f){f4.w,f5.z}; pz2[4*c+3]=(v2f){f5.x,f5.w};
      d2[4*c+0]=(v2f){1e10f,1e10f}; d2[4*c+1]=(v2f){1e10f,1e10f};
      d2[4*c+2]=(v2f){1e10f,1e10f}; d2[4*c+3]=(v2f){1e10f,1e10f};
      c4[base+8*c+0]=make_float4(f0.x,f0.y,f0.z,0.f);
      c4[base+8*c+1]=make_float4(f0.w,f1.x,f1.y,0.f);
      c4[base+8*c+2]=make_float4(f1.z,f1.w,f2.x,0.f);
      c4[base+8*c+3]=make_float4(f2.y,f2.z,f2.w,0.f);
      c4[base+8*c+4]=make_float4(f3.x,f3.y,f3.z,0.f);
      c4[base+8*c+5]=make_float4(f3.w,f4.x,f4.y,0.f);
      c4[base+8*c+6]=make_float4(f4.z,f4.w,f5.x,0.f);
      c4[base+8*c+7]=make_float4(f5.y,f5.z,f5.w,0.f);
    }
    float cx = xb[0], cy = xb[1], cz = xb[2];   // start at index 0
    for (int it=0; it<Sc; ++it){
      if (lane==0){                             // fire-and-forget centroid write
        float* o = new_xyz + ((size_t)b*Sc + it)*3;
        o[0]=cx; o[1]=cy; o[2]=cz;
      }
      v2f ncx, ncy, ncz;
      ncx.x=-cx; ncx.y=-cx; ncy.x=-cy; ncy.y=-cy; ncz.x=-cz; ncz.y=-cz;
      float bv = -1.0f;
#pragma unroll
      for (int k=0;k<32;++k){
        // exact numpy order: ((dx*dx + dy*dy) + dz*dz); x+(-c) == x-c bitwise
        const v2f dx = pk_add(px2[k], ncx);
        const v2f dy = pk_add(py2[k], ncy);
        const v2f dz = pk_add(pz2[k], ncz);
        const v2f dd = pk_add(pk_add(pk_mul(dx,dx), pk_mul(dy,dy)), pk_mul(dz,dz));
        v2f dn;
        dn.x = fminf(d2[k].x, dd.x);
        dn.y = fminf(d2[k].y, dd.y);
        d2[k] = dn;
        bv = fmaxf(bv, fmaxf(dn.x, dn.y));      // max3-foldable
      }
      // lane-local lowest matching index (parallel min tree)
      unsigned bi = 0xFFFFFFFFu;
#pragma unroll
      for (int k=0;k<32;++k){
        const unsigned c0 = (d2[k].x == bv) ? (unsigned)(base + 2*k    ) : 0xFFFFFFFFu;
        const unsigned c1 = (d2[k].y == bv) ? (unsigned)(base + 2*k + 1) : 0xFFFFFFFFu;
        const unsigned cm = (c0 < c1) ? c0 : c1;
        bi = (cm < bi) ? cm : bi;
      }
      // wave max: 4x row_ror + 2 bcasts, lane63 -> broadcast
      float mv = bv;
      ROR_MAXF(mv,1); ROR_MAXF(mv,2); ROR_MAXF(mv,4); ROR_MAXF(mv,8);
      BC15_MAXF(mv); BC31_MAXF(mv);
      mv = __int_as_float(__builtin_amdgcn_readlane(__float_as_int(mv), 63));
      // lowest lane with bv == mv holds the global lowest matching index
      const unsigned long long mk = __ballot(bv == mv);
      const int sl = __ffsll(mk) - 1;
      const unsigned wbi = (unsigned)__builtin_amdgcn_readlane((int)bi, sl);
      const float4 cc = c4[wbi];                // uniform b128 broadcast read
      cx = cc.x; cy = cc.y; cz = cc.z;
    }
  } else if (bid < 520){
    // ================= points (B,C,N) -> pointsT (B,N,C) =================
    const int t  = bid - 8;                // 0..511
    const int tb = t >> 6;                 // batch
    const int n0 = (t & 63) << 6;
    float (*tile)[65] = (float(*)[65])smem;
    const int sub = tid >> 6;              // 0..3
    const int ln  = tid & 63;
#pragma unroll 4
    for (int cp=0; cp<16; ++cp){
      const int c = (cp<<2) + sub;
      tile[c][ln] = points[((size_t)(tb*64+c))*Nc + n0 + ln];
    }
    __syncthreads();
#pragma unroll 4
    for (int np=0; np<16; ++np){
      const int nl = (np<<2) + sub;
      pointsT[((size_t)(tb*Nc + n0 + nl))*64 + ln] = tile[ln][nl];
    }
  } else {
    // ================= tp[l][b][c] = gelu(t_embed[b]) @ wt_l.T + bt_l =================
    float* ge = smem;                      // [1024]
    for (int i = tid; i < Bc*128; i += 256) ge[i] = gelu_f(t_embed[i]);
    __syncthreads();
    for (int i = tid; i < 3*Bc*68; i += 256){
      const int l = i / (Bc*68);
      const int r = i - l*(Bc*68);
      const int b = r / 68;
      const int c = r - b*68;
      const int ci = (l==0) ? 67 : 64;
      float v = 0.0f;
      if (c < ci){
        const float* wt = (l==0)?wt0:((l==1)?wt1:wt2);
        const float* bt = (l==0)?bt0:((l==1)?bt1:bt2);
        const float* w = wt + c*128;
        const float* g = ge + b*128;
        float acc = 0.0f;
        for (int t2=0;t2<128;++t2) acc = fmaf(g[t2], w[t2], acc);
        v = acc + bt[c];
      }
      tp[i] = v;
    }
  }
}

// ---------------- fused ball query + gather: 1 wave per centroid ----------------
__global__ __launch_bounds__(256) void ballgather_kernel(const float* __restrict__ xyz,
    const float* __restrict__ new_xyz, const float* __restrict__ pointsT,
    float* __restrict__ X){
  const int g = (blockIdx.x<<2) + (threadIdx.x>>6);   // centroid id in [0, B*S)
  const int lane = threadIdx.x & 63;
  const int w = threadIdx.x >> 6;
  const int b = g >> 10;
  const float* xb = xyz + b*Nc*3;
  const float cx = new_xyz[g*3+0];
  const float cy = new_xyz[g*3+1];
  const float cz = new_xyz[g*3+2];
  __shared__ int sidx[4][32];
  int total = 0;
  for (int base=0; base<Nc; base+=64){
    const int i = base + lane;
    float dx=__fsub_rn(cx, xb[i*3+0]);
    float dy=__fsub_rn(cy, xb[i*3+1]);
    float dz=__fsub_rn(cz, xb[i*3+2]);
    float sq=__fadd_rn(__fadd_rn(__fmul_rn(dx,dx),__fmul_rn(dy,dy)),__fmul_rn(dz,dz));
    bool hit = !(sq > 0.04f);                     // sqr <= R^2, matching reference exactly
    unsigned long long m = __ballot(hit);
    if (hit){
      int pos = total + (int)__popcll(m & ((1ull<<lane)-1ull));
      if (pos < 32) sidx[w][pos] = i;
    }
    total += (int)__popcll(m);
    if (total >= 32) break;
  }
  // per-wave LDS: same-wave write->read ordering handled by lgkmcnt (no barrier)
  const int fill = (total < 32) ? total : 32;     // >=1 always (centroid itself is a hit)
  const int first = sidx[w][0];
  if (lane >= fill && lane < 32) sidx[w][lane] = first;
  // gather this wave's centroid: 32 rows x 68 cols
  for (int k=0; k<32; ++k){
    const int pidx = sidx[w][k];                  // uniform within wave
    const float* pt = pointsT + ((size_t)((b<<12)+pidx))*64;
    float* xr = X + (size_t)((g<<5)+k)*68;
    float v;
    if      (lane==0) v = __fsub_rn(xb[pidx*3+0], cx);
    else if (lane==1) v = __fsub_rn(xb[pidx*3+1], cy);
    else if (lane==2) v = __fsub_rn(xb[pidx*3+2], cz);
    else              v = pt[lane-3];
    xr[lane] = v;
    if (lane < 4){
      const int c = 64 + lane;
      xr[c] = (c<67) ? pt[c-3] : 0.0f;
    }
  }
}

// ---------------- 1x1 conv matmul: round-9 structure (best measured) ----------------
// 256 rows/block, 4 rows x 16 cols per thread, rolled ping-pong prefetch.
// NORMIN: x = gelu(x*sc + sh) applied to loaded input, then + tp.
// In-place safe (Y may == X): each row read/written only by 4 lanes of one wave (lockstep),
// all loads (incl. prefetch) precede stores in program order.
// NOTE: outer c-loop MUST stay rolled (#pragma unroll 1) - full unroll spilled (round 8).
template<int NORMIN, int CI_REAL, int CI_PAD, int LDX>
__global__ __launch_bounds__(256) void mm_kernel(const float* X,
    const float* __restrict__ wc, const float* __restrict__ tp,
    const float* __restrict__ sc_in, const float* __restrict__ sh_in,
    float* Y, float* __restrict__ pS, float* __restrict__ pQ, int o_base)
{
  __shared__ __align__(16) float wT[CI_PAD][64];
  __shared__ __align__(16) float tpr[CI_PAD];
  __shared__ __align__(16) float scN[64], shN[64];
  __shared__ float redS[4][64];
  __shared__ float redQ[4][64];
  const int tid = threadIdx.x;
  const int m0 = blockIdx.x << 8;
  const int b  = blockIdx.x >> 7;          // 128 blocks per batch
  for (int idx = tid; idx < CI_PAD*64; idx += 256){
    int c = idx >> 6, o = idx & 63;
    wT[c][o] = (c < CI_REAL) ? wc[(o_base + o)*CI_REAL + c] : 0.0f;
  }
  if (tid < CI_PAD) tpr[tid] = tp[b*68 + tid];
  if (NORMIN && tid < 64){ scN[tid] = sc_in[tid]; shN[tid] = sh_in[tid]; }
  __syncthreads();
  const int rg = tid >> 2, cg = tid & 3;
  const float* x0 = X + (size_t)(m0 + (rg<<2)) * LDX;
  float4 acc[4][4];
#pragma unroll
  for (int r=0;r<4;++r)
#pragma unroll
    for (int q=0;q<4;++q) acc[r][q] = make_float4(0.f,0.f,0.f,0.f);

  // ping-pong prefetch registers (one chunk = 4 rows x 4 cols)
  float4 xpf[4];
#pragma unroll
  for (int r=0;r<4;++r) xpf[r] = *reinterpret_cast<const float4*>(x0 + r*LDX);

#pragma unroll 1
  for (int c = 0; c < CI_PAD; c += 4){
    float4 xc[4];
#pragma unroll
    for (int r=0;r<4;++r) xc[r] = xpf[r];
    if (c + 4 < CI_PAD){
#pragma unroll
      for (int r=0;r<4;++r) xpf[r] = *reinterpret_cast<const float4*>(x0 + r*LDX + (c+4));
    }
    const float4 tpv = *reinterpret_cast<const float4*>(&tpr[c]);
    if (NORMIN){
      const float4 sci = *reinterpret_cast<const float4*>(&scN[c]);
      const float4 shi = *reinterpret_cast<const float4*>(&shN[c]);
#pragma unroll
      for (int r=0;r<4;++r){
        xc[r].x = gelu_f(fmaf(xc[r].x, sci.x, shi.x));
        xc[r].y = gelu_f(fmaf(xc[r].y, sci.y, shi.y));
        xc[r].z = gelu_f(fmaf(xc[r].z, sci.z, shi.z));
        xc[r].w = gelu_f(fmaf(xc[r].w, sci.w, shi.w));
      }
    }
    float4 xr[4];
#pragma unroll
    for (int r=0;r<4;++r)
      xr[r] = make_float4(xc[r].x+tpv.x, xc[r].y+tpv.y, xc[r].z+tpv.z, xc[r].w+tpv.w);
#pragma unroll
    for (int cc=0; cc<4; ++cc){
      const float* wrow = &wT[c+cc][cg<<4];
      const float4 w0 = *reinterpret_cast<const float4*>(wrow);
      const float4 w1 = *reinterpret_cast<const float4*>(wrow+4);
      const float4 w2 = *reinterpret_cast<const float4*>(wrow+8);
      const float4 w3 = *reinterpret_cast<const float4*>(wrow+12);
#pragma unroll
      for (int r=0;r<4;++r){
        const float xs = (cc==0)?xr[r].x:((cc==1)?xr[r].y:((cc==2)?xr[r].z:xr[r].w));
        acc[r][0].x = fmaf(xs, w0.x, acc[r][0].x);
        acc[r][0].y = fmaf(xs, w0.y, acc[r][0].y);
        acc[r][0].z = fmaf(xs, w0.z, acc[r][0].z);
        acc[r][0].w = fmaf(xs, w0.w, acc[r][0].w);
        acc[r][1].x = fmaf(xs, w1.x, acc[r][1].x);
        acc[r][1].y = fmaf(xs, w1.y, acc[r][1].y);
        acc[r][1].z = fmaf(xs, w1.z, acc[r][1].z);
        acc[r][1].w = fmaf(xs, w1.w, acc[r][1].w);
        acc[r][2].x = fmaf(xs, w2.x, acc[r][2].x);
        acc[r][2].y = fmaf(xs, w2.y, acc[r][2].y);
        acc[r][2].z = fmaf(xs, w2.z, acc[r][2].z);
        acc[r][2].w = fmaf(xs, w2.w, acc[r][2].w);
        acc[r][3].x = fmaf(xs, w3.x, acc[r][3].x);
        acc[r][3].y = fmaf(xs, w3.y, acc[r][3].y);
        acc[r][3].z = fmaf(xs, w3.z, acc[r][3].z);
        acc[r][3].w = fmaf(xs, w3.w, acc[r][3].w);
      }
    }
  }
  // store Y (after all loads of this thread's rows -> in-place safe within lockstep wave)
#pragma unroll
  for (int r=0;r<4;++r){
    float4* yp = reinterpret_cast<float4*>(Y + (size_t)(m0 + (rg<<2) + r)*64 + (cg<<4));
#pragma unroll
    for (int q=0;q<4;++q) yp[q] = acc[r][q];
  }
  // fused BN partials
  float4 s[4], q2[4];
#pragma unroll
  for (int q=0;q<4;++q){
    float sx=0,sy=0,sz=0,sw=0, qx=0,qy=0,qz=0,qw=0;
#pragma unroll
    for (int r=0;r<4;++r){
      sx+=acc[r][q].x; qx+=acc[r][q].x*acc[r][q].x;
      sy+=acc[r][q].y; qy+=acc[r][q].y*acc[r][q].y;
      sz+=acc[r][q].z; qz+=acc[r][q].z*acc[r][q].z;
      sw+=acc[r][q].w; qw+=acc[r][q].w*acc[r][q].w;
    }
    s[q]=make_float4(sx,sy,sz,sw); q2[q]=make_float4(qx,qy,qz,qw);
  }
  const int lane = tid & 63, wvv = tid >> 6;
#pragma unroll
  for (int off=32; off>=4; off>>=1){
#pragma unroll
    for (int q=0;q<4;++q){
      s[q].x  += __shfl_down(s[q].x,  off);
      s[q].y  += __shfl_down(s[q].y,  off);
      s[q].z  += __shfl_down(s[q].z,  off);
      s[q].w  += __shfl_down(s[q].w,  off);
      q2[q].x += __shfl_down(q2[q].x, off);
      q2[q].y += __shfl_down(q2[q].y, off);
      q2[q].z += __shfl_down(q2[q].z, off);
      q2[q].w += __shfl_down(q2[q].w, off);
    }
  }
  if (lane < 4){  // lane == cg
#pragma unroll
    for (int q=0;q<4;++q){
      redS[wvv][lane*16 + q*4 + 0] = s[q].x;
      redS[wvv][lane*16 + q*4 + 1] = s[q].y;
      redS[wvv][lane*16 + q*4 + 2] = s[q].z;
      redS[wvv][lane*16 + q*4 + 3] = s[q].w;
      redQ[wvv][lane*16 + q*4 + 0] = q2[q].x;
      redQ[wvv][lane*16 + q*4 + 1] = q2[q].y;
      redQ[wvv][lane*16 + q*4 + 2] = q2[q].z;
      redQ[wvv][lane*16 + q*4 + 3] = q2[q].w;
    }
  }
  __syncthreads();
  if (tid < 64){
    float a=0.f, bb=0.f;
#pragma unroll
    for (int w2=0; w2<4; ++w2){ a += redS[w2][tid]; bb += redQ[w2][tid]; }
    pS[(blockIdx.x<<6) + tid] = a;
    pQ[(blockIdx.x<<6) + tid] = bb;
  }
}

// ---------------- finalize BN stats -> scale/shift (4 chunks x 64 ch) ----------------
__global__ __launch_bounds__(256) void finalize_kernel(const float* __restrict__ pS,
    const float* __restrict__ pQ, const float* __restrict__ g, const float* __restrict__ be,
    float* __restrict__ scale, float* __restrict__ shift, int nblk){
  __shared__ float rS[4][64], rQ[4][64];
  const int o = threadIdx.x & 63;
  const int ch = threadIdx.x >> 6;
  const int per = nblk >> 2;
  float s=0.f, q=0.f;
  const int i0 = ch*per;
#pragma unroll 4
  for (int i=0;i<per;++i){
    s += pS[((i0+i)<<6)+o];
    q += pQ[((i0+i)<<6)+o];
  }
  rS[ch][o]=s; rQ[ch][o]=q;
  __syncthreads();
  if (threadIdx.x < 64){
    float ss = rS[0][o]+rS[1][o]+rS[2][o]+rS[3][o];
    float qq = rQ[0][o]+rQ[1][o]+rQ[2][o]+rQ[3][o];
    const float inv_n = 1.0f/(float)Mc;
    const float mu = ss*inv_n;
    const float var = qq*inv_n - mu*mu;
    const float rs = 1.0f/sqrtf(var + 1e-5f);
    const float sc = rs*g[o];
    scale[o] = sc;
    shift[o] = fmaf(-mu, sc, be[o]);
  }
}

// ---------------- layer2: normalize + GELU + max over K -> new_points (B,128,S) ----------------
__global__ __launch_bounds__(256) void pool_kernel(const float* __restrict__ Y,
    const float* __restrict__ scale, const float* __restrict__ shift,
    float* __restrict__ out, int o_base){
  __shared__ float pool[32][65];
  const int tid = threadIdx.x;
  const int b  = blockIdx.x >> 5;
  const int s0 = (blockIdx.x & 31) << 5;     // 32 centroids per block
  const int c  = tid & 63;
  const int sl0 = tid >> 6;
  const float sc = scale[c], sh = shift[c];
  for (int sp=0; sp<8; ++sp){
    const int sl = (sp<<2) + sl0;
    const int s = s0 + sl;
    const float* yp = Y + ((size_t)((b<<10)+s)<<5)*64 + c;
    float mx = -1e30f;
#pragma unroll 4
    for (int k=0;k<32;++k){
      float v = yp[(size_t)(k<<6)];
      v = gelu_f(fmaf(v, sc, sh));
      mx = fmaxf(mx, v);
    }
    pool[sl][c] = mx;
  }
  __syncthreads();
  for (int p=0;p<8;++p){
    const int c2 = (p<<3) + (tid>>5);
    const int sl = tid & 31;
    out[((size_t)((b<<7) + o_base + c2)<<10) + s0 + sl] = pool[sl][c2];
  }
}

// ---------------- launch ----------------
extern "C" void kernel_launch(void* const* d_in, const int* in_sizes, int n_in,
                              void* d_out, int out_size, void* d_ws, size_t ws_size,
                              hipStream_t stream){
  const float* xyz     = (const float*)d_in[0];
  const float* points  = (const float*)d_in[1];
  const float* t_embed = (const float*)d_in[2];
  const float* wt0=(const float*)d_in[3],  *bt0=(const float*)d_in[4],  *wc0=(const float*)d_in[5];
  const float* g0 =(const float*)d_in[7],  *be0=(const float*)d_in[8];
  const float* wt1=(const float*)d_in[9],  *bt1=(const float*)d_in[10], *wc1=(const float*)d_in[11];
  const float* g1 =(const float*)d_in[13], *be1=(const float*)d_in[14];
  const float* wt2=(const float*)d_in[15], *bt2=(const float*)d_in[16], *wc2=(const float*)d_in[17];
  const float* g2 =(const float*)d_in[19], *be2=(const float*)d_in[20];

  float* out_xyz = (float*)d_out;                    // (B,S,3)
  float* out_pts = (float*)d_out + Bc*Sc*3;          // (B,128,S)

  // workspace layout (floats); total 148.9 MB
  float* ws       = (float*)d_ws;
  float* tp       = ws + 0;                 // 2048
  float* pointsT  = ws + 2048;              // 2,097,152
  float* pS1      = ws + 2099200;           // 65,536 (old ballidx hole)
  float* pQ1      = ws + 2230272;           // 65,536
  float* X        = ws + 2361344;           // 17,825,792 (stride-68; reused as Yx later)
  float* Ya       = ws + 20187136;          // 16,777,216
  float* pS0      = ws + 36964352;          // 65,536
  float* pQ0      = ws + 37095424;          // 65,536
  float* sc0      = ws + 37226496;
  float* sh0      = sc0 + 64;
  float* sc1      = sc0 + 128;
  float* sh1      = sc0 + 192;
  float* sc2      = sc0 + 256;
  float* sh2      = sc0 + 320;
  float* sc3      = sc0 + 384;
  float* sh3      = sc0 + 448;
  float* Yx       = X;                      // layer-2 first-half output (stride 64)

  const int NBLK = Mc/256;                  // 1024 blocks per mm (round-9 geometry)

  // front: FPS (blocks 0-7, 1 wave each) + transpose (8-519) + tp MLP (520)
  fused_front_kernel<<<521, 256, 0, stream>>>(xyz, out_xyz, points, pointsT,
      t_embed, wt0,bt0, wt1,bt1, wt2,bt2, tp);
  // fused ball query + gather
  ballgather_kernel<<<(Bc*Sc)/4, 256, 0, stream>>>(xyz, out_xyz, pointsT, X);

  // layer 0: ci=67 (pad 68), co=64, no input norm
  mm_kernel<0,67,68,68><<<NBLK, 256, 0, stream>>>(X, wc0, tp, nullptr, nullptr, Ya, pS0, pQ0, 0);
  finalize_kernel<<<1, 256, 0, stream>>>(pS0, pQ0, g0, be0, sc0, sh0, NBLK);

  // layer 1: fused input norm+gelu, in-place Ya -> Ya
  mm_kernel<1,64,64,64><<<NBLK, 256, 0, stream>>>(Ya, wc1, tp + 544, sc0, sh0, Ya, pS0, pQ0, 0);
  finalize_kernel<<<1, 256, 0, stream>>>(pS0, pQ0, g1, be1, sc1, sh1, NBLK);

  // layer 2: two 64-col halves; first half Ya -> Yx, second half in-place Ya -> Ya
  mm_kernel<1,64,64,64><<<NBLK, 256, 0, stream>>>(Ya, wc2, tp + 1088, sc1, sh1, Yx, pS0, pQ0, 0);
  mm_kernel<1,64,64,64><<<NBLK, 256, 0, stream>>>(Ya, wc2, tp + 1088, sc1, sh1, Ya, pS1, pQ1, 64);
  finalize_kernel<<<1, 256, 0, stream>>>(pS0, pQ0, g2,    be2,    sc2, sh2, NBLK);
  finalize_kernel<<<1, 256, 0, stream>>>(pS1, pQ1, g2+64, be2+64, sc3, sh3, NBLK);

  pool_kernel<<<Bc*Sc/32, 256, 0, stream>>>(Yx, sc2, sh2, out_pts, 0);
  pool_kernel<<<Bc*Sc/32, 256, 0, stream>>>(Ya, sc3, sh3, out_pts, 64);
}

// Round 13
// 1211.076 us; speedup vs baseline: 1.9219x; 1.9219x over previous
//
#include <hip/hip_runtime.h>
#include <cmath>

// Problem constants (from reference setup_inputs)
#define Bc 8
#define Nc 4096
#define Sc 1024
#define Kc 32
#define Mc (Bc*Sc*Kc)   // 262144 rows

typedef float v2f __attribute__((ext_vector_type(2)));

__device__ __forceinline__ float gelu_f(float x){
  return 0.5f*x*(1.0f + erff(x*0.70710678f));
}

// Packed f32 ops via inline asm: per-element IEEE RN, immune to FMA contraction.
__device__ __forceinline__ v2f pk_add(v2f a, v2f b){
  v2f d; asm("v_pk_add_f32 %0, %1, %2" : "=v"(d) : "v"(a), "v"(b)); return d;
}
__device__ __forceinline__ v2f pk_mul(v2f a, v2f b){
  v2f d; asm("v_pk_mul_f32 %0, %1, %2" : "=v"(d) : "v"(a), "v"(b)); return d;
}

// DPP max-reduction steps (VALU-speed cross-lane). row_ror:n = 0x120|n.
#define ROR_MAXF(v, n) { int _t = __builtin_amdgcn_update_dpp(__float_as_int(v), __float_as_int(v), 0x120|(n), 0xF, 0xF, false); \
                         v = fmaxf(v, __int_as_float(_t)); }
#define BC15_MAXF(v)   { int _t = __builtin_amdgcn_update_dpp(__float_as_int(v), __float_as_int(v), 0x142, 0xA, 0xF, false); \
                         v = fmaxf(v, __int_as_float(_t)); }
#define BC31_MAXF(v)   { int _t = __builtin_amdgcn_update_dpp(__float_as_int(v), __float_as_int(v), 0x143, 0xC, 0xF, false); \
                         v = fmaxf(v, __int_as_float(_t)); }

#define TK(v_, i_) { const bool _t = ((v_) > Bv) || (((v_) == Bv) && ((i_) < Bi)); \
  Bv = _t ? (v_) : Bv; Bi = _t ? (i_) : Bi; }

// ---------------- fused front: blocks 0-7 FPS, 8-519 transpose, 520 tp-MLP ----------------
// FPS branch is the round-6 structure (best measured: 703 us across 5 variants) - frozen.
__global__ __launch_bounds__(256) void fused_front_kernel(
    const float* __restrict__ xyz, float* __restrict__ new_xyz,
    const float* __restrict__ points, float* __restrict__ pointsT,
    const float* __restrict__ t_embed,
    const float* __restrict__ wt0, const float* __restrict__ bt0,
    const float* __restrict__ wt1, const float* __restrict__ bt1,
    const float* __restrict__ wt2, const float* __restrict__ bt2,
    float* __restrict__ tp)
{
  __shared__ __align__(16) float smem[17424];   // 69.7 KB pool
  const int bid = blockIdx.x;
  const int tid = threadIdx.x;

  if (bid < 8){
    // ================= FPS: bitwise-exact vs numpy =================
    const int b = bid;
    const int lane = tid & 63;
    const int wv = tid >> 6;                    // 0..3
    const float* xb = xyz + b*Nc*3;
    float*    skv   = smem;                     // [2][4] wave best dist (parity)
    unsigned* ski   = (unsigned*)(smem + 8);    // [2][4] wave best idx
    int*      shist = (int*)(smem + 16);        // [1024] selected indices
    float4*   c4    = (float4*)(smem + 1040);   // [4096] coord stash

    const int base = tid << 4;                  // first owned point
    float4 f[12];
    const float4* src = (const float4*)(xb + base*3);
#pragma unroll
    for (int q=0;q<12;++q) f[q] = src[q];
#define AR(i) ((i)%4==0 ? f[(i)/4].x : (i)%4==1 ? f[(i)/4].y : (i)%4==2 ? f[(i)/4].z : f[(i)/4].w)
    v2f px2[8], py2[8], pz2[8], d2[8];
#pragma unroll
    for (int k=0;k<8;++k){
      px2[k].x = AR(6*k+0); py2[k].x = AR(6*k+1); pz2[k].x = AR(6*k+2);
      px2[k].y = AR(6*k+3); py2[k].y = AR(6*k+4); pz2[k].y = AR(6*k+5);
      c4[base+2*k  ] = make_float4(px2[k].x, py2[k].x, pz2[k].x, 0.f);
      c4[base+2*k+1] = make_float4(px2[k].y, py2[k].y, pz2[k].y, 0.f);
      d2[k].x = 1e10f; d2[k].y = 1e10f;
    }
#undef AR
    __syncthreads();
    int widx = 0;                               // deterministic start at index 0
    for (int it=0; it<Sc; ++it){
      const float4 cc = c4[widx];               // single b128 LDS broadcast
      if (tid==0) shist[it] = widx;
      v2f ncx, ncy, ncz;
      ncx.x=-cc.x; ncx.y=-cc.x; ncy.x=-cc.y; ncy.y=-cc.y; ncz.x=-cc.z; ncz.y=-cc.z;
      float bvx=-1.0f, bvy=-1.0f;
#pragma unroll
      for (int k=0;k<8;++k){
        // exact numpy order: ((dx*dx + dy*dy) + dz*dz); x+(-c) == x-c bitwise
        const v2f dx = pk_add(px2[k], ncx);
        const v2f dy = pk_add(py2[k], ncy);
        const v2f dz = pk_add(pz2[k], ncz);
        const v2f dd = pk_add(pk_add(pk_mul(dx,dx), pk_mul(dy,dy)), pk_mul(dz,dz));
        v2f dn;
        dn.x = fminf(d2[k].x, dd.x);
        dn.y = fminf(d2[k].y, dd.y);
        d2[k] = dn;
        bvx = fmaxf(bvx, dn.x);
        bvy = fmaxf(bvy, dn.y);
      }
      const float bv = fmaxf(bvx, bvy);
      // lane-local lowest matching index (parallel min tree)
      unsigned bi_local = 0xFFFFFFFFu;
#pragma unroll
      for (int k=0;k<8;++k){
        const unsigned c0 = (d2[k].x == bv) ? (unsigned)(base + 2*k    ) : 0xFFFFFFFFu;
        const unsigned c1 = (d2[k].y == bv) ? (unsigned)(base + 2*k + 1) : 0xFFFFFFFFu;
        const unsigned cm = (c0 < c1) ? c0 : c1;
        bi_local = (cm < bi_local) ? cm : bi_local;
      }
      // wave max (value only): 4x row_ror + 2 bcasts, lane63 -> SGPR
      float mv = bv;
      ROR_MAXF(mv,1); ROR_MAXF(mv,2); ROR_MAXF(mv,4); ROR_MAXF(mv,8);
      BC15_MAXF(mv); BC31_MAXF(mv);
      mv = __int_as_float(__builtin_amdgcn_readlane(__float_as_int(mv), 63));
      // lowest lane with bv == mv holds the lowest matching point index
      const unsigned long long mk = __ballot(bv == mv);
      const int src_lane = __ffsll(mk) - 1;
      const unsigned bi = (unsigned)__builtin_amdgcn_readlane((int)bi_local, src_lane);
      const int p4 = (it & 1) << 2;
      if (lane==0){ skv[p4+wv] = mv; ski[p4+wv] = bi; }
      __syncthreads();                          // single barrier per iteration
      const float4 m4 = *reinterpret_cast<const float4*>(&skv[p4]);
      const uint4  i4 = *reinterpret_cast<const uint4*>(&ski[p4]);
      float Bv = m4.x; unsigned Bi = i4.x;
      TK(m4.y, i4.y) TK(m4.z, i4.z) TK(m4.w, i4.w)
      widx = (int)Bi;
    }
    __syncthreads();
    // write all centroids once
    for (int i = tid; i < Sc; i += 256){
      const float4 cc = c4[shist[i]];
      float* o = new_xyz + ((size_t)b*Sc + i)*3;
      o[0]=cc.x; o[1]=cc.y; o[2]=cc.z;
    }
  } else if (bid < 520){
    // ================= points (B,C,N) -> pointsT (B,N,C) =================
    const int t  = bid - 8;                // 0..511
    const int tb = t >> 6;                 // batch
    const int n0 = (t & 63) << 6;
    float (*tile)[65] = (float(*)[65])smem;
    const int sub = tid >> 6;              // 0..3
    const int ln  = tid & 63;
#pragma unroll 4
    for (int cp=0; cp<16; ++cp){
      const int c = (cp<<2) + sub;
      tile[c][ln] = points[((size_t)(tb*64+c))*Nc + n0 + ln];
    }
    __syncthreads();
#pragma unroll 4
    for (int np=0; np<16; ++np){
      const int nl = (np<<2) + sub;
      pointsT[((size_t)(tb*Nc + n0 + nl))*64 + ln] = tile[ln][nl];
    }
  } else {
    // ================= tp[l][b][c] = gelu(t_embed[b]) @ wt_l.T + bt_l =================
    float* ge = smem;                      // [1024]
    for (int i = tid; i < Bc*128; i += 256) ge[i] = gelu_f(t_embed[i]);
    __syncthreads();
    for (int i = tid; i < 3*Bc*68; i += 256){
      const int l = i / (Bc*68);
      const int r = i - l*(Bc*68);
      const int b = r / 68;
      const int c = r - b*68;
      const int ci = (l==0) ? 67 : 64;
      float v = 0.0f;
      if (c < ci){
        const float* wt = (l==0)?wt0:((l==1)?wt1:wt2);
        const float* bt = (l==0)?bt0:((l==1)?bt1:bt2);
        const float* w = wt + c*128;
        const float* g = ge + b*128;
        float acc = 0.0f;
        for (int t2=0;t2<128;++t2) acc = fmaf(g[t2], w[t2], acc);
        v = acc + bt[c];
      }
      tp[i] = v;
    }
  }
}

// ---------------- fused ball query + gather: 1 wave per centroid ----------------
__global__ __launch_bounds__(256) void ballgather_kernel(const float* __restrict__ xyz,
    const float* __restrict__ new_xyz, const float* __restrict__ pointsT,
    float* __restrict__ X){
  const int g = (blockIdx.x<<2) + (threadIdx.x>>6);   // centroid id in [0, B*S)
  const int lane = threadIdx.x & 63;
  const int w = threadIdx.x >> 6;
  const int b = g >> 10;
  const float* xb = xyz + b*Nc*3;
  const float cx = new_xyz[g*3+0];
  const float cy = new_xyz[g*3+1];
  const float cz = new_xyz[g*3+2];
  __shared__ int sidx[4][32];
  int total = 0;
  for (int base=0; base<Nc; base+=64){
    const int i = base + lane;
    float dx=__fsub_rn(cx, xb[i*3+0]);
    float dy=__fsub_rn(cy, xb[i*3+1]);
    float dz=__fsub_rn(cz, xb[i*3+2]);
    float sq=__fadd_rn(__fadd_rn(__fmul_rn(dx,dx),__fmul_rn(dy,dy)),__fmul_rn(dz,dz));
    bool hit = !(sq > 0.04f);                     // sqr <= R^2, matching reference exactly
    unsigned long long m = __ballot(hit);
    if (hit){
      int pos = total + (int)__popcll(m & ((1ull<<lane)-1ull));
      if (pos < 32) sidx[w][pos] = i;
    }
    total += (int)__popcll(m);
    if (total >= 32) break;
  }
  // per-wave LDS: same-wave write->read ordering handled by lgkmcnt (no barrier)
  const int fill = (total < 32) ? total : 32;     // >=1 always (centroid itself is a hit)
  const int first = sidx[w][0];
  if (lane >= fill && lane < 32) sidx[w][lane] = first;
  // gather this wave's centroid: 32 rows x 68 cols
  for (int k=0; k<32; ++k){
    const int pidx = sidx[w][k];                  // uniform within wave
    const float* pt = pointsT + ((size_t)((b<<12)+pidx))*64;
    float* xr = X + (size_t)((g<<5)+k)*68;
    float v;
    if      (lane==0) v = __fsub_rn(xb[pidx*3+0], cx);
    else if (lane==1) v = __fsub_rn(xb[pidx*3+1], cy);
    else if (lane==2) v = __fsub_rn(xb[pidx*3+2], cz);
    else              v = pt[lane-3];
    xr[lane] = v;
    if (lane < 4){
      const int c = 64 + lane;
      xr[c] = (c<67) ? pt[c-3] : 0.0f;
    }
  }
}

// ---------------- 1x1 conv matmul: round-9 structure (best measured) ----------------
// 256 rows/block, 4 rows x 16 cols per thread, rolled ping-pong prefetch.
// NORMIN: x = gelu(x*sc + sh) applied to loaded input, then + tp.
// In-place safe (Y may == X): each row read/written only by 4 lanes of one wave (lockstep),
// all loads (incl. prefetch) precede stores in program order.
// NOTE: outer c-loop MUST stay rolled (#pragma unroll 1) - full unroll spilled (round 8).
template<int NORMIN, int CI_REAL, int CI_PAD, int LDX>
__global__ __launch_bounds__(256) void mm_kernel(const float* X,
    const float* __restrict__ wc, const float* __restrict__ tp,
    const float* __restrict__ sc_in, const float* __restrict__ sh_in,
    float* Y, float* __restrict__ pS, float* __restrict__ pQ, int o_base)
{
  __shared__ __align__(16) float wT[CI_PAD][64];
  __shared__ __align__(16) float tpr[CI_PAD];
  __shared__ __align__(16) float scN[64], shN[64];
  __shared__ float redS[4][64];
  __shared__ float redQ[4][64];
  const int tid = threadIdx.x;
  const int m0 = blockIdx.x << 8;
  const int b  = blockIdx.x >> 7;          // 128 blocks per batch
  for (int idx = tid; idx < CI_PAD*64; idx += 256){
    int c = idx >> 6, o = idx & 63;
    wT[c][o] = (c < CI_REAL) ? wc[(o_base + o)*CI_REAL + c] : 0.0f;
  }
  if (tid < CI_PAD) tpr[tid] = tp[b*68 + tid];
  if (NORMIN && tid < 64){ scN[tid] = sc_in[tid]; shN[tid] = sh_in[tid]; }
  __syncthreads();
  const int rg = tid >> 2, cg = tid & 3;
  const float* x0 = X + (size_t)(m0 + (rg<<2)) * LDX;
  float4 acc[4][4];
#pragma unroll
  for (int r=0;r<4;++r)
#pragma unroll
    for (int q=0;q<4;++q) acc[r][q] = make_float4(0.f,0.f,0.f,0.f);

  // ping-pong prefetch registers (one chunk = 4 rows x 4 cols)
  float4 xpf[4];
#pragma unroll
  for (int r=0;r<4;++r) xpf[r] = *reinterpret_cast<const float4*>(x0 + r*LDX);

#pragma unroll 1
  for (int c = 0; c < CI_PAD; c += 4){
    float4 xc[4];
#pragma unroll
    for (int r=0;r<4;++r) xc[r] = xpf[r];
    if (c + 4 < CI_PAD){
#pragma unroll
      for (int r=0;r<4;++r) xpf[r] = *reinterpret_cast<const float4*>(x0 + r*LDX + (c+4));
    }
    const float4 tpv = *reinterpret_cast<const float4*>(&tpr[c]);
    if (NORMIN){
      const float4 sci = *reinterpret_cast<const float4*>(&scN[c]);
      const float4 shi = *reinterpret_cast<const float4*>(&shN[c]);
#pragma unroll
      for (int r=0;r<4;++r){
        xc[r].x = gelu_f(fmaf(xc[r].x, sci.x, shi.x));
        xc[r].y = gelu_f(fmaf(xc[r].y, sci.y, shi.y));
        xc[r].z = gelu_f(fmaf(xc[r].z, sci.z, shi.z));
        xc[r].w = gelu_f(fmaf(xc[r].w, sci.w, shi.w));
      }
    }
    float4 xr[4];
#pragma unroll
    for (int r=0;r<4;++r)
      xr[r] = make_float4(xc[r].x+tpv.x, xc[r].y+tpv.y, xc[r].z+tpv.z, xc[r].w+tpv.w);
#pragma unroll
    for (int cc=0; cc<4; ++cc){
      const float* wrow = &wT[c+cc][cg<<4];
      const float4 w0 = *reinterpret_cast<const float4*>(wrow);
      const float4 w1 = *reinterpret_cast<const float4*>(wrow+4);
      const float4 w2 = *reinterpret_cast<const float4*>(wrow+8);
      const float4 w3 = *reinterpret_cast<const float4*>(wrow+12);
#pragma unroll
      for (int r=0;r<4;++r){
        const float xs = (cc==0)?xr[r].x:((cc==1)?xr[r].y:((cc==2)?xr[r].z:xr[r].w));
        acc[r][0].x = fmaf(xs, w0.x, acc[r][0].x);
        acc[r][0].y = fmaf(xs, w0.y, acc[r][0].y);
        acc[r][0].z = fmaf(xs, w0.z, acc[r][0].z);
        acc[r][0].w = fmaf(xs, w0.w, acc[r][0].w);
        acc[r][1].x = fmaf(xs, w1.x, acc[r][1].x);
        acc[r][1].y = fmaf(xs, w1.y, acc[r][1].y);
        acc[r][1].z = fmaf(xs, w1.z, acc[r][1].z);
        acc[r][1].w = fmaf(xs, w1.w, acc[r][1].w);
        acc[r][2].x = fmaf(xs, w2.x, acc[r][2].x);
        acc[r][2].y = fmaf(xs, w2.y, acc[r][2].y);
        acc[r][2].z = fmaf(xs, w2.z, acc[r][2].z);
        acc[r][2].w = fmaf(xs, w2.w, acc[r][2].w);
        acc[r][3].x = fmaf(xs, w3.x, acc[r][3].x);
        acc[r][3].y = fmaf(xs, w3.y, acc[r][3].y);
        acc[r][3].z = fmaf(xs, w3.z, acc[r][3].z);
        acc[r][3].w = fmaf(xs, w3.w, acc[r][3].w);
      }
    }
  }
  // store Y (after all loads of this thread's rows -> in-place safe within lockstep wave)
#pragma unroll
  for (int r=0;r<4;++r){
    float4* yp = reinterpret_cast<float4*>(Y + (size_t)(m0 + (rg<<2) + r)*64 + (cg<<4));
#pragma unroll
    for (int q=0;q<4;++q) yp[q] = acc[r][q];
  }
  // fused BN partials
  float4 s[4], q2[4];
#pragma unroll
  for (int q=0;q<4;++q){
    float sx=0,sy=0,sz=0,sw=0, qx=0,qy=0,qz=0,qw=0;
#pragma unroll
    for (int r=0;r<4;++r){
      sx+=acc[r][q].x; qx+=acc[r][q].x*acc[r][q].x;
      sy+=acc[r][q].y; qy+=acc[r][q].y*acc[r][q].y;
      sz+=acc[r][q].z; qz+=acc[r][q].z*acc[r][q].z;
      sw+=acc[r][q].w; qw+=acc[r][q].w*acc[r][q].w;
    }
    s[q]=make_float4(sx,sy,sz,sw); q2[q]=make_float4(qx,qy,qz,qw);
  }
  const int lane = tid & 63, wvv = tid >> 6;
#pragma unroll
  for (int off=32; off>=4; off>>=1){
#pragma unroll
    for (int q=0;q<4;++q){
      s[q].x  += __shfl_down(s[q].x,  off);
      s[q].y  += __shfl_down(s[q].y,  off);
      s[q].z  += __shfl_down(s[q].z,  off);
      s[q].w  += __shfl_down(s[q].w,  off);
      q2[q].x += __shfl_down(q2[q].x, off);
      q2[q].y += __shfl_down(q2[q].y, off);
      q2[q].z += __shfl_down(q2[q].z, off);
      q2[q].w += __shfl_down(q2[q].w, off);
    }
  }
  if (lane < 4){  // lane == cg
#pragma unroll
    for (int q=0;q<4;++q){
      redS[wvv][lane*16 + q*4 + 0] = s[q].x;
      redS[wvv][lane*16 + q*4 + 1] = s[q].y;
      redS[wvv][lane*16 + q*4 + 2] = s[q].z;
      redS[wvv][lane*16 + q*4 + 3] = s[q].w;
      redQ[wvv][lane*16 + q*4 + 0] = q2[q].x;
      redQ[wvv][lane*16 + q*4 + 1] = q2[q].y;
      redQ[wvv][lane*16 + q*4 + 2] = q2[q].z;
      redQ[wvv][lane*16 + q*4 + 3] = q2[q].w;
    }
  }
  __syncthreads();
  if (tid < 64){
    float a=0.f, bb=0.f;
#pragma unroll
    for (int w2=0; w2<4; ++w2){ a += redS[w2][tid]; bb += redQ[w2][tid]; }
    pS[(blockIdx.x<<6) + tid] = a;
    pQ[(blockIdx.x<<6) + tid] = bb;
  }
}

// ---------------- finalize BN stats -> scale/shift (1024 thr, 16 chunks x 64 ch) ----------------
__global__ __launch_bounds__(1024) void finalize_kernel(const float* __restrict__ pS,
    const float* __restrict__ pQ, const float* __restrict__ g, const float* __restrict__ be,
    float* __restrict__ scale, float* __restrict__ shift, int nblk){
  __shared__ float rS[16][64], rQ[16][64];
  const int o = threadIdx.x & 63;
  const int ch = threadIdx.x >> 6;          // 0..15
  const int per = nblk >> 4;                // 64 for nblk=1024
  float s=0.f, q=0.f;
  const int i0 = ch*per;
#pragma unroll 4
  for (int i=0;i<per;++i){
    s += pS[((i0+i)<<6)+o];
    q += pQ[((i0+i)<<6)+o];
  }
  rS[ch][o]=s; rQ[ch][o]=q;
  __syncthreads();
  if (threadIdx.x < 64){
    float ss = 0.f, qq = 0.f;
#pragma unroll
    for (int c=0;c<16;++c){ ss += rS[c][o]; qq += rQ[c][o]; }
    const float inv_n = 1.0f/(float)Mc;
    const float mu = ss*inv_n;
    const float var = qq*inv_n - mu*mu;
    const float rs = 1.0f/sqrtf(var + 1e-5f);
    const float sc = rs*g[o];
    scale[o] = sc;
    shift[o] = fmaf(-mu, sc, be[o]);
  }
}

// ---------------- layer2: normalize + GELU + max over K -> new_points (B,128,S) ----------------
__global__ __launch_bounds__(256) void pool_kernel(const float* __restrict__ Y,
    const float* __restrict__ scale, const float* __restrict__ shift,
    float* __restrict__ out, int o_base){
  __shared__ float pool[32][65];
  const int tid = threadIdx.x;
  const int b  = blockIdx.x >> 5;
  const int s0 = (blockIdx.x & 31) << 5;     // 32 centroids per block
  const int c  = tid & 63;
  const int sl0 = tid >> 6;
  const float sc = scale[c], sh = shift[c];
  for (int sp=0; sp<8; ++sp){
    const int sl = (sp<<2) + sl0;
    const int s = s0 + sl;
    const float* yp = Y + ((size_t)((b<<10)+s)<<5)*64 + c;
    float mx = -1e30f;
#pragma unroll 4
    for (int k=0;k<32;++k){
      float v = yp[(size_t)(k<<6)];
      v = gelu_f(fmaf(v, sc, sh));
      mx = fmaxf(mx, v);
    }
    pool[sl][c] = mx;
  }
  __syncthreads();
  for (int p=0;p<8;++p){
    const int c2 = (p<<3) + (tid>>5);
    const int sl = tid & 31;
    out[((size_t)((b<<7) + o_base + c2)<<10) + s0 + sl] = pool[sl][c2];
  }
}

// ---------------- launch ----------------
extern "C" void kernel_launch(void* const* d_in, const int* in_sizes, int n_in,
                              void* d_out, int out_size, void* d_ws, size_t ws_size,
                              hipStream_t stream){
  const float* xyz     = (const float*)d_in[0];
  const float* points  = (const float*)d_in[1];
  const float* t_embed = (const float*)d_in[2];
  const float* wt0=(const float*)d_in[3],  *bt0=(const float*)d_in[4],  *wc0=(const float*)d_in[5];
  const float* g0 =(const float*)d_in[7],  *be0=(const float*)d_in[8];
  const float* wt1=(const float*)d_in[9],  *bt1=(const float*)d_in[10], *wc1=(const float*)d_in[11];
  const float* g1 =(const float*)d_in[13], *be1=(const float*)d_in[14];
  const float* wt2=(const float*)d_in[15], *bt2=(const float*)d_in[16], *wc2=(const float*)d_in[17];
  const float* g2 =(const float*)d_in[19], *be2=(const float*)d_in[20];

  float* out_xyz = (float*)d_out;                    // (B,S,3)
  float* out_pts = (float*)d_out + Bc*Sc*3;          // (B,128,S)

  // workspace layout (floats); total 148.9 MB
  float* ws       = (float*)d_ws;
  float* tp       = ws + 0;                 // 2048
  float* pointsT  = ws + 2048;              // 2,097,152
  float* pS1      = ws + 2099200;           // 65,536 (old ballidx hole)
  float* pQ1      = ws + 2230272;           // 65,536
  float* X        = ws + 2361344;           // 17,825,792 (stride-68; reused as Yx later)
  float* Ya       = ws + 20187136;          // 16,777,216
  float* pS0      = ws + 36964352;          // 65,536
  float* pQ0      = ws + 37095424;          // 65,536
  float* sc0      = ws + 37226496;
  float* sh0      = sc0 + 64;
  float* sc1      = sc0 + 128;
  float* sh1      = sc0 + 192;
  float* sc2      = sc0 + 256;
  float* sh2      = sc0 + 320;
  float* sc3      = sc0 + 384;
  float* sh3      = sc0 + 448;
  float* Yx       = X;                      // layer-2 first-half output (stride 64)

  const int NBLK = Mc/256;                  // 1024 blocks per mm (round-9 geometry)

  // front: FPS (blocks 0-7) + transpose (8-519) + tp MLP (520), overlapped
  fused_front_kernel<<<521, 256, 0, stream>>>(xyz, out_xyz, points, pointsT,
      t_embed, wt0,bt0, wt1,bt1, wt2,bt2, tp);
  // fused ball query + gather
  ballgather_kernel<<<(Bc*Sc)/4, 256, 0, stream>>>(xyz, out_xyz, pointsT, X);

  // layer 0: ci=67 (pad 68), co=64, no input norm
  mm_kernel<0,67,68,68><<<NBLK, 256, 0, stream>>>(X, wc0, tp, nullptr, nullptr, Ya, pS0, pQ0, 0);
  finalize_kernel<<<1, 1024, 0, stream>>>(pS0, pQ0, g0, be0, sc0, sh0, NBLK);

  // layer 1: fused input norm+gelu, in-place Ya -> Ya
  mm_kernel<1,64,64,64><<<NBLK, 256, 0, stream>>>(Ya, wc1, tp + 544, sc0, sh0, Ya, pS0, pQ0, 0);
  finalize_kernel<<<1, 1024, 0, stream>>>(pS0, pQ0, g1, be1, sc1, sh1, NBLK);

  // layer 2: two 64-col halves; first half Ya -> Yx, second half in-place Ya -> Ya
  mm_kernel<1,64,64,64><<<NBLK, 256, 0, stream>>>(Ya, wc2, tp + 1088, sc1, sh1, Yx, pS0, pQ0, 0);
  mm_kernel<1,64,64,64><<<NBLK, 256, 0, stream>>>(Ya, wc2, tp + 1088, sc1, sh1, Ya, pS1, pQ1, 64);
  finalize_kernel<<<1, 1024, 0, stream>>>(pS0, pQ0, g2,    be2,    sc2, sh2, NBLK);
  finalize_kernel<<<1, 1024, 0, stream>>>(pS1, pQ1, g2+64, be2+64, sc3, sh3, NBLK);

  pool_kernel<<<Bc*Sc/32, 256, 0, stream>>>(Yx, sc2, sh2, out_pts, 0);
  pool_kernel<<<Bc*Sc/32, 256, 0, stream>>>(Ya, sc3, sh3, out_pts, 64);
}

// Round 14
// 1175.492 us; speedup vs baseline: 1.9801x; 1.0303x over previous
//
#include <hip/hip_runtime.h>
#include <cmath>

// Problem constants (from reference setup_inputs)
#define Bc 8
#define Nc 4096
#define Sc 1024
#define Kc 32
#define Mc (Bc*Sc*Kc)   // 262144 rows

typedef float v2f __attribute__((ext_vector_type(2)));

__device__ __forceinline__ float gelu_f(float x){
  return 0.5f*x*(1.0f + erff(x*0.70710678f));
}

// Packed f32 ops via inline asm: per-element IEEE RN, immune to FMA contraction.
__device__ __forceinline__ v2f pk_add(v2f a, v2f b){
  v2f d; asm("v_pk_add_f32 %0, %1, %2" : "=v"(d) : "v"(a), "v"(b)); return d;
}
__device__ __forceinline__ v2f pk_mul(v2f a, v2f b){
  v2f d; asm("v_pk_mul_f32 %0, %1, %2" : "=v"(d) : "v"(a), "v"(b)); return d;
}

// DPP max-reduction steps (VALU-speed cross-lane). row_ror:n = 0x120|n.
#define ROR_MAXF(v, n) { int _t = __builtin_amdgcn_update_dpp(__float_as_int(v), __float_as_int(v), 0x120|(n), 0xF, 0xF, false); \
                         v = fmaxf(v, __int_as_float(_t)); }
#define BC15_MAXF(v)   { int _t = __builtin_amdgcn_update_dpp(__float_as_int(v), __float_as_int(v), 0x142, 0xA, 0xF, false); \
                         v = fmaxf(v, __int_as_float(_t)); }
#define BC31_MAXF(v)   { int _t = __builtin_amdgcn_update_dpp(__float_as_int(v), __float_as_int(v), 0x143, 0xC, 0xF, false); \
                         v = fmaxf(v, __int_as_float(_t)); }

#define TK(v_, i_) { const bool _t = ((v_) > Bv) || (((v_) == Bv) && ((i_) < Bi)); \
  Bv = _t ? (v_) : Bv; Bi = _t ? (i_) : Bi; }

// ---------------- fused front: blocks 0-7 FPS, 8-519 transpose, 520 tp-MLP ----------------
// FPS branch is the round-6 structure (best measured: 703 us across 5 variants) - frozen.
__global__ __launch_bounds__(256) void fused_front_kernel(
    const float* __restrict__ xyz, float* __restrict__ new_xyz,
    const float* __restrict__ points, float* __restrict__ pointsT,
    const float* __restrict__ t_embed,
    const float* __restrict__ wt0, const float* __restrict__ bt0,
    const float* __restrict__ wt1, const float* __restrict__ bt1,
    const float* __restrict__ wt2, const float* __restrict__ bt2,
    float* __restrict__ tp)
{
  __shared__ __align__(16) float smem[17424];   // 69.7 KB pool
  const int bid = blockIdx.x;
  const int tid = threadIdx.x;

  if (bid < 8){
    // ================= FPS: bitwise-exact vs numpy =================
    const int b = bid;
    const int lane = tid & 63;
    const int wv = tid >> 6;                    // 0..3
    const float* xb = xyz + b*Nc*3;
    float*    skv   = smem;                     // [2][4] wave best dist (parity)
    unsigned* ski   = (unsigned*)(smem + 8);    // [2][4] wave best idx
    int*      shist = (int*)(smem + 16);        // [1024] selected indices
    float4*   c4    = (float4*)(smem + 1040);   // [4096] coord stash

    const int base = tid << 4;                  // first owned point
    float4 f[12];
    const float4* src = (const float4*)(xb + base*3);
#pragma unroll
    for (int q=0;q<12;++q) f[q] = src[q];
#define AR(i) ((i)%4==0 ? f[(i)/4].x : (i)%4==1 ? f[(i)/4].y : (i)%4==2 ? f[(i)/4].z : f[(i)/4].w)
    v2f px2[8], py2[8], pz2[8], d2[8];
#pragma unroll
    for (int k=0;k<8;++k){
      px2[k].x = AR(6*k+0); py2[k].x = AR(6*k+1); pz2[k].x = AR(6*k+2);
      px2[k].y = AR(6*k+3); py2[k].y = AR(6*k+4); pz2[k].y = AR(6*k+5);
      c4[base+2*k  ] = make_float4(px2[k].x, py2[k].x, pz2[k].x, 0.f);
      c4[base+2*k+1] = make_float4(px2[k].y, py2[k].y, pz2[k].y, 0.f);
      d2[k].x = 1e10f; d2[k].y = 1e10f;
    }
#undef AR
    __syncthreads();
    int widx = 0;                               // deterministic start at index 0
    for (int it=0; it<Sc; ++it){
      const float4 cc = c4[widx];               // single b128 LDS broadcast
      if (tid==0) shist[it] = widx;
      v2f ncx, ncy, ncz;
      ncx.x=-cc.x; ncx.y=-cc.x; ncy.x=-cc.y; ncy.y=-cc.y; ncz.x=-cc.z; ncz.y=-cc.z;
      float bvx=-1.0f, bvy=-1.0f;
#pragma unroll
      for (int k=0;k<8;++k){
        // exact numpy order: ((dx*dx + dy*dy) + dz*dz); x+(-c) == x-c bitwise
        const v2f dx = pk_add(px2[k], ncx);
        const v2f dy = pk_add(py2[k], ncy);
        const v2f dz = pk_add(pz2[k], ncz);
        const v2f dd = pk_add(pk_add(pk_mul(dx,dx), pk_mul(dy,dy)), pk_mul(dz,dz));
        v2f dn;
        dn.x = fminf(d2[k].x, dd.x);
        dn.y = fminf(d2[k].y, dd.y);
        d2[k] = dn;
        bvx = fmaxf(bvx, dn.x);
        bvy = fmaxf(bvy, dn.y);
      }
      const float bv = fmaxf(bvx, bvy);
      // lane-local lowest matching index (parallel min tree)
      unsigned bi_local = 0xFFFFFFFFu;
#pragma unroll
      for (int k=0;k<8;++k){
        const unsigned c0 = (d2[k].x == bv) ? (unsigned)(base + 2*k    ) : 0xFFFFFFFFu;
        const unsigned c1 = (d2[k].y == bv) ? (unsigned)(base + 2*k + 1) : 0xFFFFFFFFu;
        const unsigned cm = (c0 < c1) ? c0 : c1;
        bi_local = (cm < bi_local) ? cm : bi_local;
      }
      // wave max (value only): 4x row_ror + 2 bcasts, lane63 -> SGPR
      float mv = bv;
      ROR_MAXF(mv,1); ROR_MAXF(mv,2); ROR_MAXF(mv,4); ROR_MAXF(mv,8);
      BC15_MAXF(mv); BC31_MAXF(mv);
      mv = __int_as_float(__builtin_amdgcn_readlane(__float_as_int(mv), 63));
      // lowest lane with bv == mv holds the lowest matching point index
      const unsigned long long mk = __ballot(bv == mv);
      const int src_lane = __ffsll(mk) - 1;
      const unsigned bi = (unsigned)__builtin_amdgcn_readlane((int)bi_local, src_lane);
      const int p4 = (it & 1) << 2;
      if (lane==0){ skv[p4+wv] = mv; ski[p4+wv] = bi; }
      __syncthreads();                          // single barrier per iteration
      const float4 m4 = *reinterpret_cast<const float4*>(&skv[p4]);
      const uint4  i4 = *reinterpret_cast<const uint4*>(&ski[p4]);
      float Bv = m4.x; unsigned Bi = i4.x;
      TK(m4.y, i4.y) TK(m4.z, i4.z) TK(m4.w, i4.w)
      widx = (int)Bi;
    }
    __syncthreads();
    // write all centroids once
    for (int i = tid; i < Sc; i += 256){
      const float4 cc = c4[shist[i]];
      float* o = new_xyz + ((size_t)b*Sc + i)*3;
      o[0]=cc.x; o[1]=cc.y; o[2]=cc.z;
    }
  } else if (bid < 520){
    // ================= points (B,C,N) -> pointsT (B,N,C) =================
    const int t  = bid - 8;                // 0..511
    const int tb = t >> 6;                 // batch
    const int n0 = (t & 63) << 6;
    float (*tile)[65] = (float(*)[65])smem;
    const int sub = tid >> 6;              // 0..3
    const int ln  = tid & 63;
#pragma unroll 4
    for (int cp=0; cp<16; ++cp){
      const int c = (cp<<2) + sub;
      tile[c][ln] = points[((size_t)(tb*64+c))*Nc + n0 + ln];
    }
    __syncthreads();
#pragma unroll 4
    for (int np=0; np<16; ++np){
      const int nl = (np<<2) + sub;
      pointsT[((size_t)(tb*Nc + n0 + nl))*64 + ln] = tile[ln][nl];
    }
  } else {
    // ================= tp[l][b][c] = gelu(t_embed[b]) @ wt_l.T + bt_l =================
    float* ge = smem;                      // [1024]
    for (int i = tid; i < Bc*128; i += 256) ge[i] = gelu_f(t_embed[i]);
    __syncthreads();
    for (int i = tid; i < 3*Bc*68; i += 256){
      const int l = i / (Bc*68);
      const int r = i - l*(Bc*68);
      const int b = r / 68;
      const int c = r - b*68;
      const int ci = (l==0) ? 67 : 64;
      float v = 0.0f;
      if (c < ci){
        const float* wt = (l==0)?wt0:((l==1)?wt1:wt2);
        const float* bt = (l==0)?bt0:((l==1)?bt1:bt2);
        const float* w = wt + c*128;
        const float* g = ge + b*128;
        float acc = 0.0f;
        for (int t2=0;t2<128;++t2) acc = fmaf(g[t2], w[t2], acc);
        v = acc + bt[c];
      }
      tp[i] = v;
    }
  }
}

// ---------------- fused ball query + gather: 1 wave per centroid ----------------
__global__ __launch_bounds__(256) void ballgather_kernel(const float* __restrict__ xyz,
    const float* __restrict__ new_xyz, const float* __restrict__ pointsT,
    float* __restrict__ X){
  const int g = (blockIdx.x<<2) + (threadIdx.x>>6);   // centroid id in [0, B*S)
  const int lane = threadIdx.x & 63;
  const int w = threadIdx.x >> 6;
  const int b = g >> 10;
  const float* xb = xyz + b*Nc*3;
  const float cx = new_xyz[g*3+0];
  const float cy = new_xyz[g*3+1];
  const float cz = new_xyz[g*3+2];
  __shared__ int sidx[4][32];
  int total = 0;
  for (int base=0; base<Nc; base+=64){
    const int i = base + lane;
    float dx=__fsub_rn(cx, xb[i*3+0]);
    float dy=__fsub_rn(cy, xb[i*3+1]);
    float dz=__fsub_rn(cz, xb[i*3+2]);
    float sq=__fadd_rn(__fadd_rn(__fmul_rn(dx,dx),__fmul_rn(dy,dy)),__fmul_rn(dz,dz));
    bool hit = !(sq > 0.04f);                     // sqr <= R^2, matching reference exactly
    unsigned long long m = __ballot(hit);
    if (hit){
      int pos = total + (int)__popcll(m & ((1ull<<lane)-1ull));
      if (pos < 32) sidx[w][pos] = i;
    }
    total += (int)__popcll(m);
    if (total >= 32) break;
  }
  // per-wave LDS: same-wave write->read ordering handled by lgkmcnt (no barrier)
  const int fill = (total < 32) ? total : 32;     // >=1 always (centroid itself is a hit)
  const int first = sidx[w][0];
  if (lane >= fill && lane < 32) sidx[w][lane] = first;
  // gather this wave's centroid: 32 rows x 68 cols
  for (int k=0; k<32; ++k){
    const int pidx = sidx[w][k];                  // uniform within wave
    const float* pt = pointsT + ((size_t)((b<<12)+pidx))*64;
    float* xr = X + (size_t)((g<<5)+k)*68;
    float v;
    if      (lane==0) v = __fsub_rn(xb[pidx*3+0], cx);
    else if (lane==1) v = __fsub_rn(xb[pidx*3+1], cy);
    else if (lane==2) v = __fsub_rn(xb[pidx*3+2], cz);
    else              v = pt[lane-3];
    xr[lane] = v;
    if (lane < 4){
      const int c = 64 + lane;
      xr[c] = (c<67) ? pt[c-3] : 0.0f;
    }
  }
}

// ---------------- 1x1 conv matmul: round-9 structure (best measured) ----------------
// 256 rows/block, 4 rows x 16 cols per thread, rolled ping-pong prefetch.
// NOTE: outer c-loop MUST stay rolled (#pragma unroll 1) - full unroll spilled (round 8).
template<int NORMIN, int CI_REAL, int CI_PAD, int LDX>
__global__ __launch_bounds__(256) void mm_kernel(const float* X,
    const float* __restrict__ wc, const float* __restrict__ tp,
    const float* __restrict__ sc_in, const float* __restrict__ sh_in,
    float* Y, float* __restrict__ pS, float* __restrict__ pQ, int o_base)
{
  __shared__ __align__(16) float wT[CI_PAD][64];
  __shared__ __align__(16) float tpr[CI_PAD];
  __shared__ __align__(16) float scN[64], shN[64];
  __shared__ float redS[4][64];
  __shared__ float redQ[4][64];
  const int tid = threadIdx.x;
  const int m0 = blockIdx.x << 8;
  const int b  = blockIdx.x >> 7;          // 128 blocks per batch
  for (int idx = tid; idx < CI_PAD*64; idx += 256){
    int c = idx >> 6, o = idx & 63;
    wT[c][o] = (c < CI_REAL) ? wc[(o_base + o)*CI_REAL + c] : 0.0f;
  }
  if (tid < CI_PAD) tpr[tid] = tp[b*68 + tid];
  if (NORMIN && tid < 64){ scN[tid] = sc_in[tid]; shN[tid] = sh_in[tid]; }
  __syncthreads();
  const int rg = tid >> 2, cg = tid & 3;
  const float* x0 = X + (size_t)(m0 + (rg<<2)) * LDX;
  float4 acc[4][4];
#pragma unroll
  for (int r=0;r<4;++r)
#pragma unroll
    for (int q=0;q<4;++q) acc[r][q] = make_float4(0.f,0.f,0.f,0.f);

  // ping-pong prefetch registers (one chunk = 4 rows x 4 cols)
  float4 xpf[4];
#pragma unroll
  for (int r=0;r<4;++r) xpf[r] = *reinterpret_cast<const float4*>(x0 + r*LDX);

#pragma unroll 1
  for (int c = 0; c < CI_PAD; c += 4){
    float4 xc[4];
#pragma unroll
    for (int r=0;r<4;++r) xc[r] = xpf[r];
    if (c + 4 < CI_PAD){
#pragma unroll
      for (int r=0;r<4;++r) xpf[r] = *reinterpret_cast<const float4*>(x0 + r*LDX + (c+4));
    }
    const float4 tpv = *reinterpret_cast<const float4*>(&tpr[c]);
    if (NORMIN){
      const float4 sci = *reinterpret_cast<const float4*>(&scN[c]);
      const float4 shi = *reinterpret_cast<const float4*>(&shN[c]);
#pragma unroll
      for (int r=0;r<4;++r){
        xc[r].x = gelu_f(fmaf(xc[r].x, sci.x, shi.x));
        xc[r].y = gelu_f(fmaf(xc[r].y, sci.y, shi.y));
        xc[r].z = gelu_f(fmaf(xc[r].z, sci.z, shi.z));
        xc[r].w = gelu_f(fmaf(xc[r].w, sci.w, shi.w));
      }
    }
    float4 xr[4];
#pragma unroll
    for (int r=0;r<4;++r)
      xr[r] = make_float4(xc[r].x+tpv.x, xc[r].y+tpv.y, xc[r].z+tpv.z, xc[r].w+tpv.w);
#pragma unroll
    for (int cc=0; cc<4; ++cc){
      const float* wrow = &wT[c+cc][cg<<4];
      const float4 w0 = *reinterpret_cast<const float4*>(wrow);
      const float4 w1 = *reinterpret_cast<const float4*>(wrow+4);
      const float4 w2 = *reinterpret_cast<const float4*>(wrow+8);
      const float4 w3 = *reinterpret_cast<const float4*>(wrow+12);
#pragma unroll
      for (int r=0;r<4;++r){
        const float xs = (cc==0)?xr[r].x:((cc==1)?xr[r].y:((cc==2)?xr[r].z:xr[r].w));
        acc[r][0].x = fmaf(xs, w0.x, acc[r][0].x);
        acc[r][0].y = fmaf(xs, w0.y, acc[r][0].y);
        acc[r][0].z = fmaf(xs, w0.z, acc[r][0].z);
        acc[r][0].w = fmaf(xs, w0.w, acc[r][0].w);
        acc[r][1].x = fmaf(xs, w1.x, acc[r][1].x);
        acc[r][1].y = fmaf(xs, w1.y, acc[r][1].y);
        acc[r][1].z = fmaf(xs, w1.z, acc[r][1].z);
        acc[r][1].w = fmaf(xs, w1.w, acc[r][1].w);
        acc[r][2].x = fmaf(xs, w2.x, acc[r][2].x);
        acc[r][2].y = fmaf(xs, w2.y, acc[r][2].y);
        acc[r][2].z = fmaf(xs, w2.z, acc[r][2].z);
        acc[r][2].w = fmaf(xs, w2.w, acc[r][2].w);
        acc[r][3].x = fmaf(xs, w3.x, acc[r][3].x);
        acc[r][3].y = fmaf(xs, w3.y, acc[r][3].y);
        acc[r][3].z = fmaf(xs, w3.z, acc[r][3].z);
        acc[r][3].w = fmaf(xs, w3.w, acc[r][3].w);
      }
    }
  }
  // store Y (after all loads of this thread's rows -> in-place safe within lockstep wave)
#pragma unroll
  for (int r=0;r<4;++r){
    float4* yp = reinterpret_cast<float4*>(Y + (size_t)(m0 + (rg<<2) + r)*64 + (cg<<4));
#pragma unroll
    for (int q=0;q<4;++q) yp[q] = acc[r][q];
  }
  // fused BN partials
  float4 s[4], q2[4];
#pragma unroll
  for (int q=0;q<4;++q){
    float sx=0,sy=0,sz=0,sw=0, qx=0,qy=0,qz=0,qw=0;
#pragma unroll
    for (int r=0;r<4;++r){
      sx+=acc[r][q].x; qx+=acc[r][q].x*acc[r][q].x;
      sy+=acc[r][q].y; qy+=acc[r][q].y*acc[r][q].y;
      sz+=acc[r][q].z; qz+=acc[r][q].z*acc[r][q].z;
      sw+=acc[r][q].w; qw+=acc[r][q].w*acc[r][q].w;
    }
    s[q]=make_float4(sx,sy,sz,sw); q2[q]=make_float4(qx,qy,qz,qw);
  }
  const int lane = tid & 63, wvv = tid >> 6;
#pragma unroll
  for (int off=32; off>=4; off>>=1){
#pragma unroll
    for (int q=0;q<4;++q){
      s[q].x  += __shfl_down(s[q].x,  off);
      s[q].y  += __shfl_down(s[q].y,  off);
      s[q].z  += __shfl_down(s[q].z,  off);
      s[q].w  += __shfl_down(s[q].w,  off);
      q2[q].x += __shfl_down(q2[q].x, off);
      q2[q].y += __shfl_down(q2[q].y, off);
      q2[q].z += __shfl_down(q2[q].z, off);
      q2[q].w += __shfl_down(q2[q].w, off);
    }
  }
  if (lane < 4){  // lane == cg
#pragma unroll
    for (int q=0;q<4;++q){
      redS[wvv][lane*16 + q*4 + 0] = s[q].x;
      redS[wvv][lane*16 + q*4 + 1] = s[q].y;
      redS[wvv][lane*16 + q*4 + 2] = s[q].z;
      redS[wvv][lane*16 + q*4 + 3] = s[q].w;
      redQ[wvv][lane*16 + q*4 + 0] = q2[q].x;
      redQ[wvv][lane*16 + q*4 + 1] = q2[q].y;
      redQ[wvv][lane*16 + q*4 + 2] = q2[q].z;
      redQ[wvv][lane*16 + q*4 + 3] = q2[q].w;
    }
  }
  __syncthreads();
  if (tid < 64){
    float a=0.f, bb=0.f;
#pragma unroll
    for (int w2=0; w2<4; ++w2){ a += redS[w2][tid]; bb += redQ[w2][tid]; }
    pS[(blockIdx.x<<6) + tid] = a;
    pQ[(blockIdx.x<<6) + tid] = bb;
  }
}

// ---------------- layer-2 merged 1x1 conv: CO=128 in one input pass ----------------
// 128 rows/block, 2 rows x 32 cols per thread (acc[2][8] = 64 VGPR, same as mm_kernel).
// Column interleave col = j*16 + cg*4: the 4 cg W-read addresses land in distinct
// LDS banks (conflict-free) AND wv stays statically indexed (rule #20).
// In-place safe on Y1 (== input buffer): row's 4 owner lanes are in one wave
// (lockstep); all loads precede stores in program order.
__global__ __launch_bounds__(256) void mm2_kernel(const float* X,
    const float* __restrict__ wc, const float* __restrict__ tp,
    const float* __restrict__ sc_in, const float* __restrict__ sh_in,
    float* Y0, float* Y1, float* __restrict__ pS, float* __restrict__ pQ)
{
  __shared__ __align__(16) float wT[64][128];   // [k][o] 32 KB
  __shared__ __align__(16) float tpr[64];
  __shared__ __align__(16) float scN[64], shN[64];
  __shared__ float redS[4][128];
  __shared__ float redQ[4][128];
  const int tid = threadIdx.x;
  const int m0 = blockIdx.x << 7;          // 128 rows per block
  const int b  = blockIdx.x >> 8;          // 256 blocks per batch
  for (int idx = tid; idx < 64*128; idx += 256){
    const int c = idx >> 7, o = idx & 127;
    wT[c][o] = wc[o*64 + c];
  }
  if (tid < 64) tpr[tid] = tp[b*68 + tid];
  else if (tid < 128) scN[tid-64] = sc_in[tid-64];
  else if (tid < 192) shN[tid-128] = sh_in[tid-128];
  __syncthreads();
  const int rg = tid >> 2, cg = tid & 3;
  const int cb = cg << 2;                  // col offset within each 16-col group
  const float* x0 = X + (size_t)(m0 + (rg<<1)) * 64;
  float4 acc[2][8];
#pragma unroll
  for (int r=0;r<2;++r)
#pragma unroll
    for (int q=0;q<8;++q) acc[r][q] = make_float4(0.f,0.f,0.f,0.f);

  float4 xpf[2];
  xpf[0] = *reinterpret_cast<const float4*>(x0);
  xpf[1] = *reinterpret_cast<const float4*>(x0 + 64);

#pragma unroll 1
  for (int c = 0; c < 64; c += 4){
    float4 xc[2]; xc[0]=xpf[0]; xc[1]=xpf[1];
    if (c + 4 < 64){
      xpf[0] = *reinterpret_cast<const float4*>(x0 + (c+4));
      xpf[1] = *reinterpret_cast<const float4*>(x0 + 64 + (c+4));
    }
    const float4 tpv = *reinterpret_cast<const float4*>(&tpr[c]);
    const float4 sci = *reinterpret_cast<const float4*>(&scN[c]);
    const float4 shi = *reinterpret_cast<const float4*>(&shN[c]);
#pragma unroll
    for (int r=0;r<2;++r){
      xc[r].x = gelu_f(fmaf(xc[r].x, sci.x, shi.x)) + tpv.x;
      xc[r].y = gelu_f(fmaf(xc[r].y, sci.y, shi.y)) + tpv.y;
      xc[r].z = gelu_f(fmaf(xc[r].z, sci.z, shi.z)) + tpv.z;
      xc[r].w = gelu_f(fmaf(xc[r].w, sci.w, shi.w)) + tpv.w;
    }
#pragma unroll
    for (int cc=0; cc<4; ++cc){
      const float xs0 = (cc==0)?xc[0].x:((cc==1)?xc[0].y:((cc==2)?xc[0].z:xc[0].w));
      const float xs1 = (cc==0)?xc[1].x:((cc==1)?xc[1].y:((cc==2)?xc[1].z:xc[1].w));
      const float* wrow = &wT[c+cc][cb];
#pragma unroll
      for (int j=0;j<8;++j){
        const float4 wv = *reinterpret_cast<const float4*>(wrow + (j<<4));
        acc[0][j].x = fmaf(xs0, wv.x, acc[0][j].x);
        acc[0][j].y = fmaf(xs0, wv.y, acc[0][j].y);
        acc[0][j].z = fmaf(xs0, wv.z, acc[0][j].z);
        acc[0][j].w = fmaf(xs0, wv.w, acc[0][j].w);
        acc[1][j].x = fmaf(xs1, wv.x, acc[1][j].x);
        acc[1][j].y = fmaf(xs1, wv.y, acc[1][j].y);
        acc[1][j].z = fmaf(xs1, wv.z, acc[1][j].z);
        acc[1][j].w = fmaf(xs1, wv.w, acc[1][j].w);
      }
    }
  }
  // stores: channel = j*16 + cb (+comp); j<4 -> Y0 (ch 0-63), j>=4 -> Y1 (ch-64)
#pragma unroll
  for (int r=0;r<2;++r){
    const size_t row = (size_t)(m0 + (rg<<1) + r);
#pragma unroll
    for (int j=0;j<8;++j){
      float* yb = (j<4) ? Y0 : Y1;
      const int col = ((j<4) ? (j<<4) : ((j-4)<<4)) + cb;
      *reinterpret_cast<float4*>(yb + row*64 + col) = acc[r][j];
    }
  }
  // BN partials: j-sequential to bound transient VGPR
  const int lane = tid & 63, wvv = tid >> 6;
#pragma unroll
  for (int j=0;j<8;++j){
    float4 s = make_float4(acc[0][j].x+acc[1][j].x, acc[0][j].y+acc[1][j].y,
                           acc[0][j].z+acc[1][j].z, acc[0][j].w+acc[1][j].w);
    float4 q2 = make_float4(acc[0][j].x*acc[0][j].x + acc[1][j].x*acc[1][j].x,
                            acc[0][j].y*acc[0][j].y + acc[1][j].y*acc[1][j].y,
                            acc[0][j].z*acc[0][j].z + acc[1][j].z*acc[1][j].z,
                            acc[0][j].w*acc[0][j].w + acc[1][j].w*acc[1][j].w);
#pragma unroll
    for (int off=32; off>=4; off>>=1){
      s.x += __shfl_down(s.x, off);   s.y += __shfl_down(s.y, off);
      s.z += __shfl_down(s.z, off);   s.w += __shfl_down(s.w, off);
      q2.x += __shfl_down(q2.x, off); q2.y += __shfl_down(q2.y, off);
      q2.z += __shfl_down(q2.z, off); q2.w += __shfl_down(q2.w, off);
    }
    if (lane < 4){                    // lane == cg
      const int ch = (j<<4) + (lane<<2);
      redS[wvv][ch+0]=s.x;  redS[wvv][ch+1]=s.y;  redS[wvv][ch+2]=s.z;  redS[wvv][ch+3]=s.w;
      redQ[wvv][ch+0]=q2.x; redQ[wvv][ch+1]=q2.y; redQ[wvv][ch+2]=q2.z; redQ[wvv][ch+3]=q2.w;
    }
  }
  __syncthreads();
  if (tid < 128){
    float a=0.f, bb=0.f;
#pragma unroll
    for (int w2=0; w2<4; ++w2){ a += redS[w2][tid]; bb += redQ[w2][tid]; }
    pS[(size_t)blockIdx.x*128 + tid] = a;
    pQ[(size_t)blockIdx.x*128 + tid] = bb;
  }
}

// ---------------- finalize BN stats -> scale/shift (1024 thr, templated CO) ----------------
template<int CO>
__global__ __launch_bounds__(1024) void finalize_kernel(const float* __restrict__ pS,
    const float* __restrict__ pQ, const float* __restrict__ g, const float* __restrict__ be,
    float* __restrict__ scale, float* __restrict__ shift, int nblk){
  __shared__ float rS[1024], rQ[1024];
  constexpr int NCH = 1024 / CO;
  const int o  = threadIdx.x & (CO-1);
  const int ch = threadIdx.x / CO;
  const int per = nblk / NCH;
  const int i0 = ch * per;
  float s=0.f, q=0.f;
#pragma unroll 4
  for (int i=0;i<per;++i){
    s += pS[(size_t)(i0+i)*CO + o];
    q += pQ[(size_t)(i0+i)*CO + o];
  }
  rS[threadIdx.x]=s; rQ[threadIdx.x]=q;
  __syncthreads();
  if (threadIdx.x < CO){
    float ss = 0.f, qq = 0.f;
#pragma unroll
    for (int c=0;c<NCH;++c){ ss += rS[c*CO+o]; qq += rQ[c*CO+o]; }
    const float inv_n = 1.0f/(float)Mc;
    const float mu = ss*inv_n;
    const float var = qq*inv_n - mu*mu;
    const float rs = 1.0f/sqrtf(var + 1e-5f);
    const float sc = rs*g[o];
    scale[o] = sc;
    shift[o] = fmaf(-mu, sc, be[o]);
  }
}

// ---------------- layer2: normalize + GELU + max over K -> new_points (B,128,S) ----------------
__global__ __launch_bounds__(256) void pool_kernel(const float* __restrict__ Y,
    const float* __restrict__ scale, const float* __restrict__ shift,
    float* __restrict__ out, int o_base){
  __shared__ float pool[32][65];
  const int tid = threadIdx.x;
  const int b  = blockIdx.x >> 5;
  const int s0 = (blockIdx.x & 31) << 5;     // 32 centroids per block
  const int c  = tid & 63;
  const int sl0 = tid >> 6;
  const float sc = scale[c], sh = shift[c];
  for (int sp=0; sp<8; ++sp){
    const int sl = (sp<<2) + sl0;
    const int s = s0 + sl;
    const float* yp = Y + ((size_t)((b<<10)+s)<<5)*64 + c;
    float mx = -1e30f;
#pragma unroll 4
    for (int k=0;k<32;++k){
      float v = yp[(size_t)(k<<6)];
      v = gelu_f(fmaf(v, sc, sh));
      mx = fmaxf(mx, v);
    }
    pool[sl][c] = mx;
  }
  __syncthreads();
  for (int p=0;p<8;++p){
    const int c2 = (p<<3) + (tid>>5);
    const int sl = tid & 31;
    out[((size_t)((b<<7) + o_base + c2)<<10) + s0 + sl] = pool[sl][c2];
  }
}

// ---------------- launch ----------------
extern "C" void kernel_launch(void* const* d_in, const int* in_sizes, int n_in,
                              void* d_out, int out_size, void* d_ws, size_t ws_size,
                              hipStream_t stream){
  const float* xyz     = (const float*)d_in[0];
  const float* points  = (const float*)d_in[1];
  const float* t_embed = (const float*)d_in[2];
  const float* wt0=(const float*)d_in[3],  *bt0=(const float*)d_in[4],  *wc0=(const float*)d_in[5];
  const float* g0 =(const float*)d_in[7],  *be0=(const float*)d_in[8];
  const float* wt1=(const float*)d_in[9],  *bt1=(const float*)d_in[10], *wc1=(const float*)d_in[11];
  const float* g1 =(const float*)d_in[13], *be1=(const float*)d_in[14];
  const float* wt2=(const float*)d_in[15], *bt2=(const float*)d_in[16], *wc2=(const float*)d_in[17];
  const float* g2 =(const float*)d_in[19], *be2=(const float*)d_in[20];

  float* out_xyz = (float*)d_out;                    // (B,S,3)
  float* out_pts = (float*)d_out + Bc*Sc*3;          // (B,128,S)

  // workspace layout (floats); total 148.9 MB
  float* ws       = (float*)d_ws;
  float* tp       = ws + 0;                 // 2048
  float* pointsT  = ws + 2048;              // 2,097,152
  float* pS       = ws + 2099200;           // 262,144 (ends exactly at X)
  float* X        = ws + 2361344;           // 17,825,792 (stride-68; reused as Yx later)
  float* Ya       = ws + 20187136;          // 16,777,216
  float* pQ       = ws + 36964352;          // 262,144 (ends exactly at sc0)
  float* sc0      = ws + 37226496;
  float* sh0      = sc0 + 64;
  float* sc1      = sc0 + 128;
  float* sh1      = sc0 + 192;
  float* sc2      = sc0 + 256;              // 128 entries
  float* sh2      = sc0 + 384;              // 128 entries
  float* Yx       = X;                      // layer-2 first-half output (stride 64)

  const int NBLK = Mc/256;                  // 1024 blocks (layers 0/1)

  // front: FPS (blocks 0-7) + transpose (8-519) + tp MLP (520), overlapped
  fused_front_kernel<<<521, 256, 0, stream>>>(xyz, out_xyz, points, pointsT,
      t_embed, wt0,bt0, wt1,bt1, wt2,bt2, tp);
  // fused ball query + gather
  ballgather_kernel<<<(Bc*Sc)/4, 256, 0, stream>>>(xyz, out_xyz, pointsT, X);

  // layer 0: ci=67 (pad 68), co=64, no input norm
  mm_kernel<0,67,68,68><<<NBLK, 256, 0, stream>>>(X, wc0, tp, nullptr, nullptr, Ya, pS, pQ, 0);
  finalize_kernel<64><<<1, 1024, 0, stream>>>(pS, pQ, g0, be0, sc0, sh0, NBLK);

  // layer 1: fused input norm+gelu, in-place Ya -> Ya
  mm_kernel<1,64,64,64><<<NBLK, 256, 0, stream>>>(Ya, wc1, tp + 544, sc0, sh0, Ya, pS, pQ, 0);
  finalize_kernel<64><<<1, 1024, 0, stream>>>(pS, pQ, g1, be1, sc1, sh1, NBLK);

  // layer 2: merged co=128, one input pass; ch 0-63 -> Yx, ch 64-127 -> Ya (in-place)
  mm2_kernel<<<Mc/128, 256, 0, stream>>>(Ya, wc2, tp + 1088, sc1, sh1, Yx, Ya, pS, pQ);
  finalize_kernel<128><<<1, 1024, 0, stream>>>(pS, pQ, g2, be2, sc2, sh2, Mc/128);

  pool_kernel<<<Bc*Sc/32, 256, 0, stream>>>(Yx, sc2,    sh2,    out_pts, 0);
  pool_kernel<<<Bc*Sc/32, 256, 0, stream>>>(Ya, sc2+64, sh2+64, out_pts, 64);
}